// Round 10
// baseline (273.067 us; speedup 1.0000x reference)
//
#include <hip/hip_runtime.h>

#define NB 32      // B
#define NS 8192    // S
#define NH 256     // H
#define NR 256     // RIN
#define NQ 256     // QIN

typedef __bf16 bf16x8 __attribute__((ext_vector_type(8)));
typedef float  f32x4  __attribute__((ext_vector_type(4)));

__device__ __forceinline__ float fast_tanh(float x) {
  x = fminf(15.0f, fmaxf(-15.0f, x));
  float e = __expf(2.0f * x);
  return (e - 1.0f) * __builtin_amdgcn_rcpf(e + 1.0f);
}

// split 8 consecutive f32 into bf16 hi + bf16 lo (RNE): x ~= hi + lo
__device__ __forceinline__ void split8(float4 a, float4 b, bf16x8& hi, bf16x8& lo) {
  float x[8] = {a.x, a.y, a.z, a.w, b.x, b.y, b.z, b.w};
#pragma unroll
  for (int j = 0; j < 8; ++j) {
    __bf16 h = (__bf16)x[j];
    hi[j] = h;
    lo[j] = (__bf16)(x[j] - (float)h);
  }
}

// blocks 0..31: q[b,h] = query[b,:]@Wq[h,:] + bq[h]
// blocks 32..63: split Wr into fragment-linear hi/lo bf16: [ks][mtile(16)][lane][8]
//   element = Wr[16*mt + (l&15)][32*ks + 8*(l>>4) + j]
__global__ __launch_bounds__(256) void prep_kernel(
    const float* __restrict__ query, const float* __restrict__ Wq,
    const float* __restrict__ bq, const float* __restrict__ Wr,
    float* __restrict__ ws_q, __bf16* __restrict__ wsAhi, __bf16* __restrict__ wsAlo) {
  const int tid = threadIdx.x;
  const int blk = blockIdx.x;
  if (blk < NB) {
    const float4* qr = reinterpret_cast<const float4*>(query + blk * NQ);
    const float4* wr = reinterpret_cast<const float4*>(Wq + tid * NQ);
    float acc = 0.0f;
#pragma unroll 8
    for (int i = 0; i < NQ / 4; ++i) {
      float4 a = qr[i], w = wr[i];
      acc += a.x * w.x + a.y * w.y + a.z * w.z + a.w * w.w;
    }
    ws_q[blk * NH + tid] = acc + bq[tid];
  } else {
    const int gid = (blk - NB) * 256 + tid;   // [ks(8)][mt(16)][lane(64)]
    const int l  = gid & 63;
    const int mt = (gid >> 6) & 15;
    const int ks = gid >> 10;
    const int row = 16 * mt + (l & 15);
    const int kb  = 32 * ks + 8 * (l >> 4);
    const float4* src = reinterpret_cast<const float4*>(Wr + row * NR + kb);
    bf16x8 hi, lo;
    split8(src[0], src[1], hi, lo);
    *reinterpret_cast<bf16x8*>(wsAhi + (size_t)gid * 8) = hi;
    *reinterpret_cast<bf16x8*>(wsAlo + (size_t)gid * 8) = lo;
  }
}

// R9: h-chunked, ZERO-barrier kernel. Block = (hc: 64 h) x (sc: 256 s) x b.
// grid.x = hc + 4*sc (hc fastest -> the 4 sibling blocks sharing ref rows are
// dispatch-adjacent, so L3 serves their redundant reads).
// Wave wm owns s in [sc*256 + 64*wm, +64); acc[mt(4 h-sub)][nt(4 s-sub)] like R0.
// B-frags load directly from ref: per instr = 16 complete 128B lines (k-slice of
// 16 s-rows). e-writes: 64 h-rows x 1KB contiguous per block, line-complete per wave.
// u: in-wave shfl reduction over 64 h -> partial per hc into ws; reduce kernel sums.
__global__ __launch_bounds__(256, 2) void attn_kernel(
    const float* __restrict__ ref, const float* __restrict__ br,
    const float* __restrict__ v, const float* __restrict__ ws_q,
    const __bf16* __restrict__ wsAhi, const __bf16* __restrict__ wsAlo,
    float* __restrict__ e_out, float* __restrict__ u_ws) {
  const int tid = threadIdx.x;
  const int l   = tid & 63;
  const int wm  = tid >> 6;
  const int hc  = blockIdx.x & 3;
  const int sc  = blockIdx.x >> 2;
  const int b   = blockIdx.y;
  const int sbase = sc * 256 + wm * 64;

  // lane's B source row for nt=0; nt advances by 16 s-rows = 16*NB*NR floats
  const float* srcX = ref + (size_t)(sbase + (l & 15)) * (NB * NR)
                          + (size_t)b * NR + 8 * (l >> 4);
  const size_t ntStride = (size_t)16 * NB * NR;

  f32x4 acc[4][4];
  const f32x4 zero = {0.f, 0.f, 0.f, 0.f};
#pragma unroll
  for (int mt = 0; mt < 4; ++mt)
#pragma unroll
    for (int nt = 0; nt < 4; ++nt) acc[mt][nt] = zero;

  // prologue: B data for ks=0
  float4 cb[4][2];
#pragma unroll
  for (int nt = 0; nt < 4; ++nt) {
    cb[nt][0] = *reinterpret_cast<const float4*>(srcX + nt * ntStride);
    cb[nt][1] = *reinterpret_cast<const float4*>(srcX + nt * ntStride + 4);
  }

#pragma unroll 1
  for (int ks = 0; ks < NR / 32; ++ks) {
    // issue next-iter B loads first (HBM/L3; latency covered by this iter)
    const int kofs = (ks < NR / 32 - 1) ? (ks + 1) * 32 : ks * 32;
    float4 nb[4][2];
#pragma unroll
    for (int nt = 0; nt < 4; ++nt) {
      nb[nt][0] = *reinterpret_cast<const float4*>(srcX + nt * ntStride + kofs);
      nb[nt][1] = *reinterpret_cast<const float4*>(srcX + nt * ntStride + kofs + 4);
    }
    // A-frags (L2-resident pre-split Wr); mtile_global = 4*hc + mt
    bf16x8 ah[4], al[4];
#pragma unroll
    for (int mt = 0; mt < 4; ++mt) {
      const size_t fo = ((size_t)(ks * 16 + 4 * hc + mt) * 64 + l) * 8;
      ah[mt] = *reinterpret_cast<const bf16x8*>(wsAhi + fo);
      al[mt] = *reinterpret_cast<const bf16x8*>(wsAlo + fo);
    }
    // split current B (loaded last iter) — VALU covers A-load latency
    bf16x8 bh[4], bl[4];
#pragma unroll
    for (int nt = 0; nt < 4; ++nt) split8(cb[nt][0], cb[nt][1], bh[nt], bl[nt]);

    __builtin_amdgcn_s_setprio(1);
#pragma unroll
    for (int mt = 0; mt < 4; ++mt) {
#pragma unroll
      for (int nt = 0; nt < 4; ++nt) {
        acc[mt][nt] = __builtin_amdgcn_mfma_f32_16x16x32_bf16(ah[mt], bh[nt], acc[mt][nt], 0, 0, 0);
        acc[mt][nt] = __builtin_amdgcn_mfma_f32_16x16x32_bf16(ah[mt], bl[nt], acc[mt][nt], 0, 0, 0);
        acc[mt][nt] = __builtin_amdgcn_mfma_f32_16x16x32_bf16(al[mt], bh[nt], acc[mt][nt], 0, 0, 0);
      }
    }
    __builtin_amdgcn_s_setprio(0);
#pragma unroll
    for (int nt = 0; nt < 4; ++nt) { cb[nt][0] = nb[nt][0]; cb[nt][1] = nb[nt][1]; }
  }

  // Epilogue. D layout: col(lane&15) = s-sub, row(4*(lane>>4)+reg) = h-sub
  const int col = l & 15;
  const int rq  = l >> 4;
  float psum[4] = {0.f, 0.f, 0.f, 0.f};
#pragma unroll
  for (int mt = 0; mt < 4; ++mt) {
#pragma unroll
    for (int r = 0; r < 4; ++r) {
      const int h = 64 * hc + 16 * mt + 4 * rq + r;
      const float brv = br[h];
      const float qv  = ws_q[b * NH + h];
      const float vv  = v[h];
#pragma unroll
      for (int nt = 0; nt < 4; ++nt) {
        float e = acc[mt][nt][r] + brv;
        e_out[(size_t)b * NH * NS + (size_t)h * NS + (sbase + 16 * nt + col)] = e;
        psum[nt] += vv * fast_tanh(qv + e);
      }
    }
  }
  // reduce over the block's 64 h (across rq groups); store partial for this hc
#pragma unroll
  for (int nt = 0; nt < 4; ++nt) {
    float p = psum[nt];
    p += __shfl_xor(p, 16, 64);
    p += __shfl_xor(p, 32, 64);
    if (rq == 0)
      u_ws[((size_t)hc * NB + b) * NS + sbase + 16 * nt + col] = p;
  }
}

// u_out[b][s] = 10*tanh( sum_hc u_ws[hc][b][s] ); 256K elems, f32x4 per thread
__global__ __launch_bounds__(256) void ured_kernel(
    const float* __restrict__ u_ws, float* __restrict__ u_out) {
  const int i4 = blockIdx.x * 256 + threadIdx.x;   // 0..65535, each = 4 floats
  f32x4 u = *reinterpret_cast<const f32x4*>(u_ws + (size_t)4 * i4);
#pragma unroll
  for (int hc = 1; hc < 4; ++hc) {
    f32x4 t = *reinterpret_cast<const f32x4*>(u_ws + (size_t)hc * NB * NS + 4 * i4);
#pragma unroll
    for (int r = 0; r < 4; ++r) u[r] += t[r];
  }
  f32x4 o;
#pragma unroll
  for (int r = 0; r < 4; ++r) o[r] = 10.0f * fast_tanh(u[r]);
  *reinterpret_cast<f32x4*>(u_out + (size_t)4 * i4) = o;
}

extern "C" void kernel_launch(void* const* d_in, const int* in_sizes, int n_in,
                              void* d_out, int out_size, void* d_ws, size_t ws_size,
                              hipStream_t stream) {
  const float* query = (const float*)d_in[0];
  const float* ref   = (const float*)d_in[1];
  const float* Wq    = (const float*)d_in[2];
  const float* bq    = (const float*)d_in[3];
  const float* Wr    = (const float*)d_in[4];
  const float* br    = (const float*)d_in[5];
  const float* v     = (const float*)d_in[6];

  float* e_out = (float*)d_out;                       // [B][H][S]
  float* u_out = e_out + (size_t)NB * NH * NS;        // [B][S]

  // ws: q 32KB | Wr-hi 128KB | Wr-lo 128KB | u partials 4MB ([hc(4)][B][S] f32)
  float*  ws_q  = (float*)d_ws;
  __bf16* wsAhi = (__bf16*)((char*)d_ws + 32 * 1024);
  __bf16* wsAlo = (__bf16*)((char*)d_ws + 32 * 1024 + 128 * 1024);
  float*  u_ws  = (float*)((char*)d_ws + 32 * 1024 + 256 * 1024);

  prep_kernel<<<dim3(NB + 32), 256, 0, stream>>>(query, Wq, bq, Wr, ws_q, wsAhi, wsAlo);
  attn_kernel<<<dim3(4 * (NS / 256), NB), 256, 0, stream>>>(ref, br, v, ws_q, wsAhi, wsAlo, e_out, u_ws);
  ured_kernel<<<dim3(NB * NS / 1024), 256, 0, stream>>>(u_ws, u_out);
}